// Round 10
// baseline (177.303 us; speedup 1.0000x reference)
//
#include <hip/hip_runtime.h>
#include <hip/hip_bf16.h>
#include <cstddef>

#define G_   2048
#define NPG_ 512
#define CPG_ 128
#define CPG2_ 32
#define N0_  (G_*NPG_)
#define M1_  (G_*CPG_)
#define M2_  (G_*CPG2_)

// output layout (floats): z_what[G,64] | z_mask[G,64] | mu[G,128] | sigma[G,128] | f[G,256]
#define OFF_ZW 0
#define OFF_ZM (G_*64)
#define OFF_MU (2*G_*64)
#define OFF_SG (2*G_*64 + G_*128)
#define OFF_F  (2*G_*64 + 2*G_*128)

typedef __attribute__((ext_vector_type(8))) short bf16x8;
typedef __attribute__((ext_vector_type(4))) float f32x4;

__device__ __forceinline__ float celu_f(float x)     { return x > 0.f ? x : __expf(x) - 1.f; }
__device__ __forceinline__ float softplus_f(float x) { return fmaxf(x, 0.f) + __logf(1.f + __expf(-fabsf(x))); }
__device__ __forceinline__ unsigned short f2bf(float x) {
    __hip_bfloat16 h = __float2bfloat16(x);
    return *reinterpret_cast<unsigned short*>(&h);
}

// ---------------- conv1: counting-sort (wave-scan) + folded weight prep ----------------
__global__ __launch_bounds__(256, 6) void k_conv1(
    const float* __restrict__ rgb, const float* __restrict__ pos, const float* __restrict__ pos1,
    const int* __restrict__ idx0, const float* __restrict__ W1l, const float* __restrict__ b1l,
    const float* __restrict__ W1g, const float* __restrict__ b1g, unsigned short* __restrict__ f1,
    const float* __restrict__ W2l, const float* __restrict__ W2g, const float* __restrict__ W3l,
    const float* __restrict__ W3g, const float* __restrict__ Wlin,
    unsigned short* __restrict__ w2lT, unsigned short* __restrict__ w2gT,
    unsigned short* __restrict__ w3lT, unsigned short* __restrict__ w3gT,
    unsigned short* __restrict__ wlinT)
{
    const int g = blockIdx.x, t = threadIdx.x;

    // folded prep: bf16 transposed weight copies (grid-stride; conv2/conv3 run after this kernel)
    {
        const size_t tid = (size_t)g*256 + t, stride = (size_t)gridDim.x*256;
        for (size_t i = tid; i < 64*64; i += stride) {        // W2l [35,64] -> [ch][k=64pad]
            const int ch = i >> 6, k = i & 63;
            w2lT[i] = f2bf(k < 35 ? W2l[k*64 + ch] : 0.f);
        }
        for (size_t i = tid; i < 128*64; i += stride) {       // W2g [64,128] -> [ch][k]
            const int ch = i >> 6, k = i & 63;
            w2gT[i] = f2bf(W2g[k*128 + ch]);
        }
        for (size_t i = tid; i < 128*160; i += stride) {      // W3l [131,128] -> [ch][k=160pad]
            const int ch = i / 160, k = i % 160;
            w3lT[i] = f2bf(k < 131 ? W3l[k*128 + ch] : 0.f);
        }
        for (size_t i = tid; i < 256*128; i += stride) {      // W3g [128,256] -> [ch][k=128]
            const int ch = i >> 7, k = i & 127;
            w3gT[i] = f2bf(W3g[k*256 + ch]);
        }
        for (size_t i = tid; i < 256*256; i += stride) {      // Wlin [256,256] -> [ch][k=256]
            const int ch = i >> 8, k = i & 255;
            wlinT[i] = f2bf(Wlin[k*256 + ch]);
        }
    }

    __shared__ float sx0[NPG_], srx[NPG_], sry[NPG_], srz[NPG_];
    __shared__ unsigned short slc1[NPG_], order[NPG_];
    __shared__ int cnt[CPG_], start[CPG_], ctr[CPG_], scan[CPG_];
    __shared__ float aggT[CPG_*20];
    __shared__ float sW1g[512];

    for (int i = t; i < 512; i += 256) sW1g[i] = W1g[i];
    if (t < CPG_) cnt[t] = 0;
    __syncthreads();

    // Phase A: stage + count
    #pragma unroll
    for (int r = 0; r < 2; r++) {
        const int lp = r*256 + t;
        const int p  = g*NPG_ + lp;
        const int c  = idx0[p];
        const int lc = c - g*CPG_;
        sx0[lp] = rgb[p];
        srx[lp] = pos[p*3+0] - pos1[c*3+0];
        sry[lp] = pos[p*3+1] - pos1[c*3+1];
        srz[lp] = pos[p*3+2] - pos1[c*3+2];
        slc1[lp] = (unsigned short)lc;
        atomicAdd(&cnt[lc], 1);
    }
    __syncthreads();

    // Phase B: wave-level inclusive scan (2 waves cover 128 clusters), 3 barriers
    if (t < CPG_) {
        int val = cnt[t];
        const int ln = t & 63;
        #pragma unroll
        for (int d = 1; d < 64; d <<= 1) {
            const int v = __shfl_up(val, d, 64);
            if (ln >= d) val += v;
        }
        scan[t] = val;
    }
    __syncthreads();
    if (t >= 64 && t < CPG_) scan[t] += scan[63];
    __syncthreads();
    if (t < CPG_) { const int s = scan[t] - cnt[t]; start[t] = s; ctr[t] = s; }
    __syncthreads();

    // Phase C: scatter
    #pragma unroll
    for (int r = 0; r < 2; r++) {
        const int lp = r*256 + t;
        const int slot = atomicAdd(&ctr[slc1[lp]], 1);
        order[slot] = (unsigned short)lp;
    }
    __syncthreads();

    // Phase D: 2 threads per cluster, no atomics
    {
        const int c = t >> 1, ch0 = (t & 1) * 8;
        float wj[8], wx[8], wy[8], wz[8], bb2[8];
        #pragma unroll
        for (int j = 0; j < 8; j++) {
            wj[j] = W1l[ch0+j]; wx[j] = W1l[16+ch0+j];
            wy[j] = W1l[32+ch0+j]; wz[j] = W1l[48+ch0+j];
            bb2[j] = b1l[ch0+j];
        }
        float a[8];
        #pragma unroll
        for (int j = 0; j < 8; j++) a[j] = 0.f;
        const int n = cnt[c], base = start[c];
        for (int i = 0; i < n; i++) {
            const int lp = order[base + i];
            const float x0 = sx0[lp], rx = srx[lp], ry = sry[lp], rz = srz[lp];
            #pragma unroll
            for (int j = 0; j < 8; j++) {
                const float h = bb2[j] + x0*wj[j] + rx*wx[j] + ry*wy[j] + rz*wz[j];
                a[j] += celu_f(h);
            }
        }
        const float inv = 1.f / fmaxf((float)n, 1.f);
        #pragma unroll
        for (int j = 0; j < 8; j++) aggT[c*20 + ch0 + j] = a[j] * inv;
    }
    __syncthreads();

    // global conv: [128,16] @ [16,32] -> celu -> f1 (bf16)
    const int oc = t & 31;
    float wreg[16];
    #pragma unroll
    for (int j = 0; j < 16; j++) wreg[j] = sW1g[j*32 + oc];
    const float bg = b1g[oc];
    #pragma unroll
    for (int i = 0; i < 16; i++) {
        const int lc = (t >> 5) + i*8;
        float a = bg;
        #pragma unroll
        for (int j = 0; j < 16; j += 4) {
            const float4 a4 = *(const float4*)&aggT[lc*20 + j];
            a += a4.x*wreg[j] + a4.y*wreg[j+1] + a4.z*wreg[j+2] + a4.w*wreg[j+3];
        }
        f1[(size_t)(g*CPG_ + lc)*32 + oc] = f2bf(celu_f(a));
    }
}

// ---------------- conv2: MFMA local + MFMA segment-sum (one-hot S) + MFMA global ----------------
__global__ __launch_bounds__(256, 5) void k_conv2(
    const unsigned short* __restrict__ f1, const float* __restrict__ pos1, const float* __restrict__ pos2,
    const int* __restrict__ idx1, const unsigned short* __restrict__ w2lT, const float* __restrict__ b2l,
    const unsigned short* __restrict__ w2gT, const float* __restrict__ b2g, unsigned short* __restrict__ f2)
{
    const int g = blockIdx.x, t = threadIdx.x;
    const int lane = t & 63, wv = t >> 6;
    const int lr = lane & 15, quad = lane >> 4;
    __shared__ __align__(16) unsigned short xs16[CPG_*72];   // HT overlay after local conv
    __shared__ __align__(16) unsigned short sT[32*136];      // one-hot S^T; agg2 overlay after
    __shared__ int   slc[CPG_];
    __shared__ int   cnti[CPG2_];
    __shared__ float invc[CPG2_];
    unsigned short* const HT   = sT - 0 + 0, *const HT_unused = nullptr; // (placeholders removed below)
    unsigned short* const HTp  = xs16;   // [ch=64][e=128], stride 136
    unsigned short* const agg2 = sT;     // [s=32][ch=64],  stride 72

    // P0: zero S^T, init cnt, stage x
    for (int i = t; i < 1088; i += 256) ((uint2*)sT)[i] = make_uint2(0u, 0u);
    if (t < CPG2_) cnti[t] = 0;
    {
        const uint4 v0 = ((const uint4*)f1)[(size_t)g*512 + t*2];
        const uint4 v1 = ((const uint4*)f1)[(size_t)g*512 + t*2 + 1];
        const int row = t >> 1, col = (t & 1) * 16;
        *(uint4*)&xs16[row*72 + col]     = v0;
        *(uint4*)&xs16[row*72 + col + 8] = v1;
    }
    for (int i = t; i < 128*29; i += 256) {
        const int r = i / 29, c = 35 + (i - r*29);
        xs16[r*72 + c] = 0;
    }
    if (t < CPG_) {
        const int c2 = idx1[g*CPG_ + t];
        slc[t] = c2 - g*CPG2_;
        #pragma unroll
        for (int d = 0; d < 3; d++)
            xs16[t*72 + 32 + d] = f2bf(pos1[(g*CPG_ + t)*3 + d] - pos2[c2*3 + d]);
    }
    __syncthreads();

    // P1: local conv MFMA
    float hv[8][4];
    {
        const int chn = wv*16 + lr;
        const bf16x8 bw0 = *(const bf16x8*)&w2lT[chn*64 + quad*8];
        const bf16x8 bw1 = *(const bf16x8*)&w2lT[chn*64 + 32 + quad*8];
        const float bias = b2l[chn];
        #pragma unroll
        for (int m = 0; m < 8; m++) {
            f32x4 acc = (f32x4){bias, bias, bias, bias};
            const bf16x8 a0 = *(const bf16x8*)&xs16[(m*16 + lr)*72 + quad*8];
            const bf16x8 a1 = *(const bf16x8*)&xs16[(m*16 + lr)*72 + 32 + quad*8];
            acc = __builtin_amdgcn_mfma_f32_16x16x32_bf16(a0, bw0, acc, 0, 0, 0);
            acc = __builtin_amdgcn_mfma_f32_16x16x32_bf16(a1, bw1, acc, 0, 0, 0);
            #pragma unroll
            for (int r = 0; r < 4; r++) hv[m][r] = celu_f(acc[r]);
        }
    }
    if (t < CPG_) {
        sT[slc[t]*136 + t] = 0x3F80;
        atomicAdd(&cnti[slc[t]], 1);
    }
    __syncthreads();   // xs16 dead; HT overlay live

    // P2: store H^T bf16
    {
        const int chn = wv*16 + lr;
        #pragma unroll
        for (int m = 0; m < 8; m++) {
            uint2 p;
            p.x = (unsigned)f2bf(hv[m][0]) | ((unsigned)f2bf(hv[m][1]) << 16);
            p.y = (unsigned)f2bf(hv[m][2]) | ((unsigned)f2bf(hv[m][3]) << 16);
            *(uint2*)&HTp[chn*136 + m*16 + quad*4] = p;
        }
    }
    if (t < CPG2_) invc[t] = 1.f / fmaxf((float)cnti[t], 1.f);
    __syncthreads();

    // P3: segment-sum MFMA
    float aggv[2][4];
    {
        const int ch = wv*16 + lr;
        f32x4 acc[2];
        acc[0] = (f32x4){0.f, 0.f, 0.f, 0.f};
        acc[1] = (f32x4){0.f, 0.f, 0.f, 0.f};
        #pragma unroll
        for (int ks = 0; ks < 4; ks++) {
            const bf16x8 b = *(const bf16x8*)&HTp[ch*136 + ks*32 + quad*8];
            #pragma unroll
            for (int mt = 0; mt < 2; mt++) {
                const bf16x8 a = *(const bf16x8*)&sT[(mt*16 + lr)*136 + ks*32 + quad*8];
                acc[mt] = __builtin_amdgcn_mfma_f32_16x16x32_bf16(a, b, acc[mt], 0, 0, 0);
            }
        }
        #pragma unroll
        for (int mt = 0; mt < 2; mt++)
        #pragma unroll
        for (int r = 0; r < 4; r++) {
            const int s = mt*16 + quad*4 + r;
            aggv[mt][r] = acc[mt][r] * invc[s];
        }
    }
    __syncthreads();   // sT dead; agg2 overlay live

    // P4: store agg bf16
    {
        const int ch = wv*16 + lr;
        #pragma unroll
        for (int mt = 0; mt < 2; mt++)
        #pragma unroll
        for (int r = 0; r < 4; r++)
            agg2[(mt*16 + quad*4 + r)*72 + ch] = f2bf(aggv[mt][r]);
    }
    __syncthreads();

    // P5: global conv MFMA
    {
        f32x4 acc2[2][2];
        int   chn2[2];
        bf16x8 bw[2][2];
        #pragma unroll
        for (int nt = 0; nt < 2; nt++) {
            chn2[nt] = (wv + nt*4)*16 + lr;
            const float bias = b2g[chn2[nt]];
            #pragma unroll
            for (int mt = 0; mt < 2; mt++) acc2[nt][mt] = (f32x4){bias, bias, bias, bias};
            bw[nt][0] = *(const bf16x8*)&w2gT[chn2[nt]*64 + quad*8];
            bw[nt][1] = *(const bf16x8*)&w2gT[chn2[nt]*64 + 32 + quad*8];
        }
        #pragma unroll
        for (int ks = 0; ks < 2; ks++) {
            #pragma unroll
            for (int mt = 0; mt < 2; mt++) {
                const bf16x8 a = *(const bf16x8*)&agg2[(mt*16 + lr)*72 + ks*32 + quad*8];
                acc2[0][mt] = __builtin_amdgcn_mfma_f32_16x16x32_bf16(a, bw[0][ks], acc2[0][mt], 0, 0, 0);
                acc2[1][mt] = __builtin_amdgcn_mfma_f32_16x16x32_bf16(a, bw[1][ks], acc2[1][mt], 0, 0, 0);
            }
        }
        #pragma unroll
        for (int nt = 0; nt < 2; nt++)
        #pragma unroll
        for (int mt = 0; mt < 2; mt++)
        #pragma unroll
        for (int r = 0; r < 4; r++) {
            const int row = mt*16 + quad*4 + r;
            f2[(size_t)(g*CPG2_ + row)*128 + chn2[nt]] = f2bf(celu_f(acc2[nt][mt][r]));
        }
    }
}

// ---------------- conv3: MFMA local + MFMA gemvs (M=16 zero-padded) + sample ----------------
__global__ __launch_bounds__(256, 4) void k_conv3(
    const unsigned short* __restrict__ f2, const float* __restrict__ pos2,
    const unsigned short* __restrict__ w3lT, const float* __restrict__ b3l,
    const unsigned short* __restrict__ w3gT, const float* __restrict__ b3g,
    const unsigned short* __restrict__ wlinT, const float* __restrict__ blin,
    const float* __restrict__ eps, float* __restrict__ out)
{
    const int g0 = blockIdx.x * 2, t = threadIdx.x;
    const int lane = t & 63, wv = t >> 6;
    const int lr = lane & 15, quad = lane >> 4;
    __shared__ __align__(16) unsigned short xs16[64*168];
    __shared__ __align__(16) float red2[2*128*9];            // 9216 B; f3B (16*264 us = 8448 B) overlays
    __shared__ __align__(16) unsigned short aggB[16*136];    // A for W3g MFMA (rows 2..15 zero)
    __shared__ float outs[512];
    unsigned short* const f3B = (unsigned short*)red2;       // [16][264], rows 2..15 zero

    // stage f2 tile + pads; zero aggB
    for (int i = t; i < 1088; i += 256) ((unsigned*)aggB)[i] = 0u;
    {
        const int row = t >> 2, q = t & 3;
        const size_t base = (size_t)(g0*CPG2_ + row)*16 + q*4;
        const uint4 v0 = ((const uint4*)f2)[base + 0];
        const uint4 v1 = ((const uint4*)f2)[base + 1];
        const uint4 v2 = ((const uint4*)f2)[base + 2];
        const uint4 v3 = ((const uint4*)f2)[base + 3];
        *(uint4*)&xs16[row*168 + q*32]      = v0;
        *(uint4*)&xs16[row*168 + q*32 + 8]  = v1;
        *(uint4*)&xs16[row*168 + q*32 + 16] = v2;
        *(uint4*)&xs16[row*168 + q*32 + 24] = v3;
    }
    for (int i = t; i < 64*29; i += 256) {
        const int r = i / 29, c = 131 + (i - r*29);
        xs16[r*168 + c] = 0;
    }
    if (t < 64) {
        #pragma unroll
        for (int d = 0; d < 3; d++)
            xs16[t*168 + 128 + d] = f2bf(pos2[(g0*CPG2_ + t)*3 + d]);
    }
    __syncthreads();

    // local conv MFMA -> celu -> row partial sums into red2
    {
        f32x4 acc[2][4];
        int chn[2];
        #pragma unroll
        for (int nt = 0; nt < 2; nt++) {
            chn[nt] = (wv + nt*4)*16 + lr;
            const float bias = b3l[chn[nt]];
            #pragma unroll
            for (int mt = 0; mt < 4; mt++) acc[nt][mt] = (f32x4){bias, bias, bias, bias};
        }
        #pragma unroll
        for (int ks = 0; ks < 5; ks++) {
            const bf16x8 b0 = *(const bf16x8*)&w3lT[chn[0]*160 + ks*32 + quad*8];
            const bf16x8 b1 = *(const bf16x8*)&w3lT[chn[1]*160 + ks*32 + quad*8];
            #pragma unroll
            for (int mt = 0; mt < 4; mt++) {
                const bf16x8 a = *(const bf16x8*)&xs16[(mt*16 + lr)*168 + ks*32 + quad*8];
                acc[0][mt] = __builtin_amdgcn_mfma_f32_16x16x32_bf16(a, b0, acc[0][mt], 0, 0, 0);
                acc[1][mt] = __builtin_amdgcn_mfma_f32_16x16x32_bf16(a, b1, acc[1][mt], 0, 0, 0);
            }
        }
        #pragma unroll
        for (int nt = 0; nt < 2; nt++)
        #pragma unroll
        for (int mt = 0; mt < 4; mt++) {
            float p = celu_f(acc[nt][mt][0]) + celu_f(acc[nt][mt][1])
                    + celu_f(acc[nt][mt][2]) + celu_f(acc[nt][mt][3]);
            const int gl = mt >> 1, pidx = (mt & 1)*4 + quad;
            red2[(gl*128 + chn[nt])*9 + pidx] = p;
        }
    }
    __syncthreads();

    // mean reduce -> aggB bf16 rows 0..1
    if (t < 256) {
        const int gl = t >> 7, ch = t & 127;
        const float* rp = &red2[(gl*128 + ch)*9];
        float a = 0.f;
        #pragma unroll
        for (int p = 0; p < 8; p++) a += rp[p];
        aggB[gl*136 + ch] = f2bf(a * (1.f/32.f));
    }
    __syncthreads();   // red2 dead after this barrier (all reads done)

    // zero f3B rows 2..15 (rows 0,1 fully written by W3g phase)
    for (int i = t; i < 14*264; i += 256) f3B[2*264 + i] = 0;

    // W3g MFMA: C[16,256] = aggB[16,128] @ W3g ; rows 0,1 valid
    {
        f32x4 c3[4];
        int ch3[4];
        #pragma unroll
        for (int nt = 0; nt < 4; nt++) {
            ch3[nt] = (wv + nt*4)*16 + lr;
            const float bias = b3g[ch3[nt]];
            c3[nt] = (f32x4){bias, bias, bias, bias};
        }
        #pragma unroll
        for (int ks = 0; ks < 4; ks++) {
            const bf16x8 a = *(const bf16x8*)&aggB[lr*136 + ks*32 + quad*8];
            #pragma unroll
            for (int nt = 0; nt < 4; nt++) {
                const bf16x8 b = *(const bf16x8*)&w3gT[ch3[nt]*128 + ks*32 + quad*8];
                c3[nt] = __builtin_amdgcn_mfma_f32_16x16x32_bf16(a, b, c3[nt], 0, 0, 0);
            }
        }
        if (quad == 0) {
            #pragma unroll
            for (int nt = 0; nt < 4; nt++) {
                const float v0 = celu_f(c3[nt][0]);   // row 0 = glimpse g0
                const float v1 = celu_f(c3[nt][1]);   // row 1 = glimpse g0+1
                out[OFF_F + (size_t)g0*256 + ch3[nt]]     = v0;
                out[OFF_F + (size_t)(g0+1)*256 + ch3[nt]] = v1;
                f3B[ch3[nt]]       = f2bf(v0);
                f3B[264 + ch3[nt]] = f2bf(v1);
            }
        }
    }
    __syncthreads();

    // Wlin MFMA: C[16,256] = f3B[16,256] @ Wlin ; rows 0,1 -> outs
    {
        f32x4 cl[4];
        int ch4[4];
        #pragma unroll
        for (int nt = 0; nt < 4; nt++) {
            ch4[nt] = (wv + nt*4)*16 + lr;
            const float bias = blin[ch4[nt]];
            cl[nt] = (f32x4){bias, bias, bias, bias};
        }
        #pragma unroll
        for (int ks = 0; ks < 8; ks++) {
            const bf16x8 a = *(const bf16x8*)&f3B[lr*264 + ks*32 + quad*8];
            #pragma unroll
            for (int nt = 0; nt < 4; nt++) {
                const bf16x8 b = *(const bf16x8*)&wlinT[ch4[nt]*256 + ks*32 + quad*8];
                cl[nt] = __builtin_amdgcn_mfma_f32_16x16x32_bf16(a, b, cl[nt], 0, 0, 0);
            }
        }
        if (quad == 0) {
            #pragma unroll
            for (int nt = 0; nt < 4; nt++) {
                outs[ch4[nt]]       = cl[nt][0];
                outs[256 + ch4[nt]] = cl[nt][1];
            }
        }
    }
    __syncthreads();

    if (t < 128) {
        #pragma unroll
        for (int gl = 0; gl < 2; gl++) {
            const int g = g0 + gl;
            const float mu    = outs[gl*256 + t];
            const float sigma = softplus_f(outs[gl*256 + 128 + t]);
            const float z     = mu + sigma * eps[g*128 + t];
            out[OFF_MU + g*128 + t] = mu;
            out[OFF_SG + g*128 + t] = sigma;
            if (t < 64) out[OFF_ZW + g*64 + t] = z;
            else        out[OFF_ZM + g*64 + (t - 64)] = z;
        }
    }
}

extern "C" void kernel_launch(void* const* d_in, const int* in_sizes, int n_in,
                              void* d_out, int out_size, void* d_ws, size_t ws_size,
                              hipStream_t stream)
{
    const float* rgb  = (const float*)d_in[0];
    const float* pos  = (const float*)d_in[1];
    const float* pos1 = (const float*)d_in[2];
    const float* pos2 = (const float*)d_in[3];
    const int*   idx0 = (const int*)d_in[4];
    const int*   idx1 = (const int*)d_in[5];
    const float* eps  = (const float*)d_in[7];
    const float* W1l = (const float*)d_in[8],  *b1l = (const float*)d_in[9];
    const float* W1g = (const float*)d_in[10], *b1g = (const float*)d_in[11];
    const float* W2l = (const float*)d_in[12], *b2l = (const float*)d_in[13];
    const float* W2g = (const float*)d_in[14], *b2g = (const float*)d_in[15];
    const float* W3l = (const float*)d_in[16], *b3l = (const float*)d_in[17];
    const float* W3g = (const float*)d_in[18], *b3g = (const float*)d_in[19];
    const float* Wlin = (const float*)d_in[20], *blin = (const float*)d_in[21];

    unsigned short* f1    = (unsigned short*)d_ws;       // M1*32 bf16
    unsigned short* f2    = f1 + (size_t)M1_*32;         // M2*128 bf16
    unsigned short* w2lT  = f2 + (size_t)M2_*128;        // 64*64
    unsigned short* w2gT  = w2lT + 64*64;                // 128*64
    unsigned short* w3lT  = w2gT + 128*64;               // 128*160
    unsigned short* w3gT  = w3lT + 128*160;              // 256*128
    unsigned short* wlinT = w3gT + 256*128;              // 256*256
    float* outp = (float*)d_out;

    k_conv1<<<G_,   256, 0, stream>>>(rgb, pos, pos1, idx0, W1l, b1l, W1g, b1g, f1,
                                      W2l, W2g, W3l, W3g, Wlin,
                                      w2lT, w2gT, w3lT, w3gT, wlinT);
    k_conv2<<<G_,   256, 0, stream>>>(f1, pos1, pos2, idx1, w2lT, b2l, w2gT, b2g, f2);
    k_conv3<<<G_/2, 256, 0, stream>>>(f2, pos2, w3lT, b3l, w3gT, b3g, wlinT, blin, eps, outp);
}